// Round 1
// baseline (2197.108 us; speedup 1.0000x reference)
//
#include <hip/hip_runtime.h>
#include <cstdint>
#include <cstddef>

// Problem constants (match reference)
#define B_ 256
#define T_ 128
#define I_ 512
#define H_ 1024
#define O_ 512
static constexpr float ALPHA = 1.0f / 20.0f;   // DT/TAU
static constexpr float THR   = 1.0f;

// ---------------------------------------------------------------------------
// Tiled fp32 GEMM:  C[m, n] = act( A[m, :] @ Bw[:, n] + bias[n] )
// BM=BN=128, BK=16, 256 threads, 8x8 micro-tile per thread.
// PERM_X: A rows are indexed m = t*B_ + b but stored as x[b, t, :] (row b*T_+t).
// RELU:   apply max(0, .) in epilogue.
// M, N, K are assumed multiples of 128/128/16 (true for all calls here).
// ---------------------------------------------------------------------------
template<bool PERM_X, bool RELU>
__global__ __launch_bounds__(256)
void gemm128(const float* __restrict__ A, const float* __restrict__ Bw,
             const float* __restrict__ bias, float* __restrict__ C,
             int M, int N, int K) {
    constexpr int BM = 128, BN = 128, BK = 16, TM = 8, TN = 8;
    __shared__ float As[BK][BM];        // [k][m] (A transposed in LDS)
    __shared__ float Bs[BK][BN + 4];    // [k][n], padded

    const int tid = threadIdx.x;
    const int ntile = N / BN;
    const int bx = blockIdx.x % ntile;      // column tile
    const int by = blockIdx.x / ntile;      // row tile
    const int row0 = by * BM, col0 = bx * BN;
    const int tx = tid & 15;                // 0..15 -> cols
    const int ty = tid >> 4;                // 0..15 -> rows

    float acc[TM][TN] = {};

    for (int k0 = 0; k0 < K; k0 += BK) {
        // ---- load A tile: 128 rows x 16 k  (512 float4, 2 per thread) ----
#pragma unroll
        for (int p = 0; p < 2; ++p) {
            int f = tid + p * 256;
            int r  = f >> 2;               // 0..127 row within tile
            int kc = (f & 3) << 2;         // 0,4,8,12
            int m = row0 + r;
            const float* arow;
            if (PERM_X) {
                int t = m >> 8;            // m / B_   (B_ == 256)
                int b = m & 255;           // m % B_
                arow = A + (size_t)(b * T_ + t) * K;
            } else {
                arow = A + (size_t)m * K;
            }
            float4 v = *reinterpret_cast<const float4*>(arow + k0 + kc);
            As[kc + 0][r] = v.x;
            As[kc + 1][r] = v.y;
            As[kc + 2][r] = v.z;
            As[kc + 3][r] = v.w;
        }
        // ---- load B tile: 16 k-rows x 128 cols (512 float4, 2 per thread) ----
#pragma unroll
        for (int p = 0; p < 2; ++p) {
            int f = tid + p * 256;
            int r  = f >> 5;               // 0..15  k-row
            int nc = (f & 31) << 2;        // 0..124 col
            float4 v = *reinterpret_cast<const float4*>(Bw + (size_t)(k0 + r) * N + col0 + nc);
            *reinterpret_cast<float4*>(&Bs[r][nc]) = v;
        }
        __syncthreads();

        // ---- FMA inner loop ----
#pragma unroll
        for (int k = 0; k < BK; ++k) {
            float a[TM], b[TN];
#pragma unroll
            for (int i = 0; i < TM; ++i) a[i] = As[k][ty * TM + i];
#pragma unroll
            for (int j = 0; j < TN; ++j) b[j] = Bs[k][tx * TN + j];
#pragma unroll
            for (int i = 0; i < TM; ++i)
#pragma unroll
                for (int j = 0; j < TN; ++j)
                    acc[i][j] += a[i] * b[j];
        }
        __syncthreads();
    }

    // ---- epilogue: bias (+ReLU), float4 stores ----
#pragma unroll
    for (int i = 0; i < TM; ++i) {
        size_t m = (size_t)(row0 + ty * TM + i);
#pragma unroll
        for (int jj = 0; jj < TN; jj += 4) {
            int n = col0 + tx * TN + jj;
            float4 c4;
            float c0 = acc[i][jj + 0] + bias[n + 0];
            float c1 = acc[i][jj + 1] + bias[n + 1];
            float c2 = acc[i][jj + 2] + bias[n + 2];
            float c3 = acc[i][jj + 3] + bias[n + 3];
            if (RELU) {
                c0 = fmaxf(c0, 0.f); c1 = fmaxf(c1, 0.f);
                c2 = fmaxf(c2, 0.f); c3 = fmaxf(c3, 0.f);
            }
            c4.x = c0; c4.y = c1; c4.z = c2; c4.w = c3;
            *reinterpret_cast<float4*>(C + m * N + n) = c4;
        }
    }
}

// ---------------------------------------------------------------------------
// LIF time-scan, in place: buf holds inputs laid out [T][BH]; after the scan
// it holds the spikes. One lane per (b, feature) pair; the T loop is the only
// sequential part of the whole network.
// ---------------------------------------------------------------------------
__global__ __launch_bounds__(256)
void lif_scan(float* __restrict__ buf, int BH) {
    int j = blockIdx.x * 256 + threadIdx.x;
    if (j >= BH) return;
    float v = 0.f;
    for (int t = 0; t < T_; ++t) {
        size_t idx = (size_t)t * BH + j;
        float in = buf[idx];
        v = v + (in - v) * ALPHA;
        bool sp = (v >= THR);
        buf[idx] = sp ? 1.0f : 0.0f;
        v = sp ? 0.0f : v;
    }
}

// Folded output weights: Wf = W2 @ Wo  (f64 accumulation), bf = b2 @ Wo + bo.
__global__ __launch_bounds__(256)
void make_wf(const float* __restrict__ W2, const float* __restrict__ Wo,
             const float* __restrict__ b2, const float* __restrict__ bo,
             float* __restrict__ Wf, float* __restrict__ bf) {
    int idx = blockIdx.x * 256 + threadIdx.x;
    if (idx < H_ * O_) {
        int h = idx / O_;
        int o = idx - h * O_;
        double acc = 0.0;
        for (int k = 0; k < H_; ++k)
            acc += (double)W2[(size_t)h * H_ + k] * (double)Wo[(size_t)k * O_ + o];
        Wf[idx] = (float)acc;
    }
    if (idx < O_) {
        double acc = (double)bo[idx];
        for (int h = 0; h < H_; ++h)
            acc += (double)b2[h] * (double)Wo[(size_t)h * O_ + idx];
        bf[idx] = (float)acc;
    }
}

__global__ __launch_bounds__(256)
void copy_last(const float* __restrict__ SO, float* __restrict__ dst) {
    int j = blockIdx.x * 256 + threadIdx.x;
    if (j < B_ * O_) dst[j] = SO[(size_t)(T_ - 1) * B_ * O_ + j];
}

// ---------------------------------------------------------------------------
extern "C" void kernel_launch(void* const* d_in, const int* in_sizes, int n_in,
                              void* d_out, int out_size, void* d_ws, size_t ws_size,
                              hipStream_t stream) {
    const float* x  = (const float*)d_in[0];
    const float* We = (const float*)d_in[1];
    const float* be = (const float*)d_in[2];
    const float* W1 = (const float*)d_in[3];
    const float* b1 = (const float*)d_in[4];
    const float* W2 = (const float*)d_in[5];
    const float* b2 = (const float*)d_in[6];
    const float* Wo = (const float*)d_in[7];
    const float* bo = (const float*)d_in[8];

    float* out = (float*)d_out;
    float* so_last = out;                              // [B, O]
    float* S1 = out + (size_t)B_ * O_;                 // [T, B, H]
    float* S2 = S1 + (size_t)T_ * B_ * H_;             // [T, B, H]
    float* SO = S2 + (size_t)T_ * B_ * H_;             // [T, B, O]

    const int TB = T_ * B_;                            // 32768 rows
    dim3 blk(256);

    // Layer 0: h_pre = relu(x @ We + be) for ALL timesteps at once -> S1 slot
    gemm128<true, true><<<dim3((TB / 128) * (H_ / 128)), blk, 0, stream>>>(
        x, We, be, S1, TB, H_, I_);
    // scan -> S1 spikes (in place)
    lif_scan<<<dim3((B_ * H_ + 255) / 256), blk, 0, stream>>>(S1, B_ * H_);

    // Layer 1: a1 = S1 @ W1 + b1 -> S2 slot
    gemm128<false, false><<<dim3((TB / 128) * (H_ / 128)), blk, 0, stream>>>(
        S1, W1, b1, S2, TB, H_, H_);
    lif_scan<<<dim3((B_ * H_ + 255) / 256), blk, 0, stream>>>(S2, B_ * H_);

    // Output layer: a2 = (S2 @ W2 + b2) @ Wo + bo -> SO slot
    size_t need_unfolded = (size_t)TB * H_ * sizeof(float);       // 128 MiB
    if (ws_size >= need_unfolded) {
        float* Abuf = (float*)d_ws;
        gemm128<false, false><<<dim3((TB / 128) * (H_ / 128)), blk, 0, stream>>>(
            S2, W2, b2, Abuf, TB, H_, H_);
        gemm128<false, false><<<dim3((TB / 128) * (O_ / 128)), blk, 0, stream>>>(
            Abuf, Wo, bo, SO, TB, O_, H_);
    } else {
        // fold: Wf = W2 @ Wo (f64 accum), bf = b2 @ Wo + bo; a2 = S2 @ Wf + bf
        float* Wf = (float*)d_ws;
        float* bf = Wf + (size_t)H_ * O_;
        make_wf<<<dim3((H_ * O_ + 255) / 256), blk, 0, stream>>>(W2, Wo, b2, bo, Wf, bf);
        gemm128<false, false><<<dim3((TB / 128) * (O_ / 128)), blk, 0, stream>>>(
            S2, Wf, bf, SO, TB, O_, H_);
    }
    lif_scan<<<dim3((B_ * O_ + 255) / 256), blk, 0, stream>>>(SO, B_ * O_);

    // Output 0: SO at last timestep
    copy_last<<<dim3((B_ * O_ + 255) / 256), blk, 0, stream>>>(SO, so_last);
}

// Round 2
// 1054.755 us; speedup vs baseline: 2.0831x; 2.0831x over previous
//
#include <hip/hip_runtime.h>
#include <cstdint>
#include <cstddef>

// Problem constants (match reference)
#define B_ 256
#define T_ 128
#define I_ 512
#define H_ 1024
#define O_ 512
static constexpr float ALPHA = 1.0f / 20.0f;   // DT/TAU
static constexpr float THR   = 1.0f;

typedef __attribute__((ext_vector_type(8))) short bf16x8;
typedef __attribute__((ext_vector_type(4))) float f32x4;

// ---------------------------------------------------------------------------
// fp32 tiled GEMM (unchanged, proven): C = act(A @ Bw + bias)
// ---------------------------------------------------------------------------
template<bool PERM_X, bool RELU>
__global__ __launch_bounds__(256)
void gemm128(const float* __restrict__ A, const float* __restrict__ Bw,
             const float* __restrict__ bias, float* __restrict__ C,
             int M, int N, int K) {
    constexpr int BM = 128, BN = 128, BK = 16, TM = 8, TN = 8;
    __shared__ float As[BK][BM];
    __shared__ float Bs[BK][BN + 4];

    const int tid = threadIdx.x;
    const int ntile = N / BN;
    const int bx = blockIdx.x % ntile;
    const int by = blockIdx.x / ntile;
    const int row0 = by * BM, col0 = bx * BN;
    const int tx = tid & 15;
    const int ty = tid >> 4;

    float acc[TM][TN] = {};

    for (int k0 = 0; k0 < K; k0 += BK) {
#pragma unroll
        for (int p = 0; p < 2; ++p) {
            int f = tid + p * 256;
            int r  = f >> 2;
            int kc = (f & 3) << 2;
            int m = row0 + r;
            const float* arow;
            if (PERM_X) {
                int t = m >> 8;
                int b = m & 255;
                arow = A + (size_t)(b * T_ + t) * K;
            } else {
                arow = A + (size_t)m * K;
            }
            float4 v = *reinterpret_cast<const float4*>(arow + k0 + kc);
            As[kc + 0][r] = v.x;
            As[kc + 1][r] = v.y;
            As[kc + 2][r] = v.z;
            As[kc + 3][r] = v.w;
        }
#pragma unroll
        for (int p = 0; p < 2; ++p) {
            int f = tid + p * 256;
            int r  = f >> 5;
            int nc = (f & 31) << 2;
            float4 v = *reinterpret_cast<const float4*>(Bw + (size_t)(k0 + r) * N + col0 + nc);
            *reinterpret_cast<float4*>(&Bs[r][nc]) = v;
        }
        __syncthreads();

#pragma unroll
        for (int k = 0; k < BK; ++k) {
            float a[TM], b[TN];
#pragma unroll
            for (int i = 0; i < TM; ++i) a[i] = As[k][ty * TM + i];
#pragma unroll
            for (int j = 0; j < TN; ++j) b[j] = Bs[k][tx * TN + j];
#pragma unroll
            for (int i = 0; i < TM; ++i)
#pragma unroll
                for (int j = 0; j < TN; ++j)
                    acc[i][j] += a[i] * b[j];
        }
        __syncthreads();
    }

#pragma unroll
    for (int i = 0; i < TM; ++i) {
        size_t m = (size_t)(row0 + ty * TM + i);
#pragma unroll
        for (int jj = 0; jj < TN; jj += 4) {
            int n = col0 + tx * TN + jj;
            float4 c4;
            float c0 = acc[i][jj + 0] + bias[n + 0];
            float c1 = acc[i][jj + 1] + bias[n + 1];
            float c2 = acc[i][jj + 2] + bias[n + 2];
            float c3 = acc[i][jj + 3] + bias[n + 3];
            if (RELU) {
                c0 = fmaxf(c0, 0.f); c1 = fmaxf(c1, 0.f);
                c2 = fmaxf(c2, 0.f); c3 = fmaxf(c3, 0.f);
            }
            c4.x = c0; c4.y = c1; c4.z = c2; c4.w = c3;
            *reinterpret_cast<float4*>(C + m * N + n) = c4;
        }
    }
}

// ---------------------------------------------------------------------------
// bf16-MFMA GEMM with 3-way weight split (fp32-equivalent precision):
//   C[M,N] = A(fp32, binary 0/1) @ (B0+B1+B2)(bf16, stored [N][K]) + bias
// 128x128 tile, BK=32, 4 waves (2x2, 64x64 each), 16x16x32 MFMA.
// ---------------------------------------------------------------------------
__device__ inline void gload_lds16(const void* gsrc, void* ldsdst) {
    __builtin_amdgcn_global_load_lds(
        (const __attribute__((address_space(1))) unsigned int*)gsrc,
        (__attribute__((address_space(3))) unsigned int*)ldsdst, 16, 0, 0);
}

__global__ __launch_bounds__(256)
void gemm_mfma3(const float* __restrict__ A,           // [M][K] fp32 spikes
                const unsigned short* __restrict__ B0, // [N][K] bf16 splits
                const unsigned short* __restrict__ B1,
                const unsigned short* __restrict__ B2,
                const float* __restrict__ bias,
                float* __restrict__ C, int M, int N, int K) {
    constexpr int BM = 128, BN = 128, BK = 32;
    __shared__ unsigned short Alds[BM * BK];        // 8 KB, [m][k]
    __shared__ unsigned short Blds[3][BN * BK];     // 24 KB, [n][k]

    const int tid  = threadIdx.x;
    const int lane = tid & 63;
    const int w    = tid >> 6;            // wave 0..3
    const int wr   = w >> 1, wc = w & 1;  // 2x2 wave grid, 64x64 each
    const int ntile = N / BN;
    const int bx = blockIdx.x % ntile;
    const int by = blockIdx.x / ntile;
    const int row0 = by * BM, col0 = bx * BN;

    const unsigned short* Bsplit[3] = {B0, B1, B2};

    f32x4 acc[4][4];
#pragma unroll
    for (int mi = 0; mi < 4; ++mi)
#pragma unroll
        for (int ni = 0; ni < 4; ++ni) {
            acc[mi][ni].x = 0.f; acc[mi][ni].y = 0.f;
            acc[mi][ni].z = 0.f; acc[mi][ni].w = 0.f;
        }

    for (int k0 = 0; k0 < K; k0 += BK) {
        // --- stage B splits via global_load_lds (dest = wave base + lane*16) ---
#pragma unroll
        for (int s = 0; s < 3; ++s) {
#pragma unroll
            for (int p = 0; p < 2; ++p) {
                int chunk = w * 2 + p;                 // 0..7, 1 KiB each
                int r  = chunk * 16 + (lane >> 2);     // n within tile, 0..127
                int kq = lane & 3;                     // 16B quad along k
                const unsigned short* src =
                    Bsplit[s] + (size_t)(col0 + r) * K + k0 + kq * 8;
                gload_lds16(src, &Blds[s][chunk * 512]);
            }
        }
        // --- stage A: fp32 -> bf16 (truncation, exact for 0/1 spikes) ---
#pragma unroll
        for (int p = 0; p < 4; ++p) {
            int c = tid + p * 256;       // 0..1023 float4-chunks
            int r = c >> 3;              // row 0..127
            int q = c & 7;               // float4 along k
            float4 v = *reinterpret_cast<const float4*>(
                A + (size_t)(row0 + r) * K + k0 + q * 4);
            uint32_t ux = __float_as_uint(v.x), uy = __float_as_uint(v.y);
            uint32_t uz = __float_as_uint(v.z), uw = __float_as_uint(v.w);
            uint2 d;
            d.x = (ux >> 16) | (uy & 0xFFFF0000u);
            d.y = (uz >> 16) | (uw & 0xFFFF0000u);
            *reinterpret_cast<uint2*>(&Alds[r * BK + q * 4]) = d;
        }
        __syncthreads();

        // --- compute: 4 A-frags, 12 B-frags, 48 MFMAs ---
        bf16x8 af[4];
#pragma unroll
        for (int mi = 0; mi < 4; ++mi)
            af[mi] = *reinterpret_cast<const bf16x8*>(
                &Alds[(wr * 64 + mi * 16 + (lane & 15)) * BK + (lane >> 4) * 8]);
#pragma unroll
        for (int s = 0; s < 3; ++s) {
#pragma unroll
            for (int ni = 0; ni < 4; ++ni) {
                bf16x8 bfrag = *reinterpret_cast<const bf16x8*>(
                    &Blds[s][(wc * 64 + ni * 16 + (lane & 15)) * BK + (lane >> 4) * 8]);
#pragma unroll
                for (int mi = 0; mi < 4; ++mi)
                    acc[mi][ni] = __builtin_amdgcn_mfma_f32_16x16x32_bf16(
                        af[mi], bfrag, acc[mi][ni], 0, 0, 0);
            }
        }
        __syncthreads();
    }

    // --- epilogue: bias + fp32 store (C/D: col=lane&15, row=(lane>>4)*4+r) ---
#pragma unroll
    for (int ni = 0; ni < 4; ++ni) {
        int col = col0 + wc * 64 + ni * 16 + (lane & 15);
        float bv = bias[col];
#pragma unroll
        for (int mi = 0; mi < 4; ++mi) {
            int rowb = row0 + wr * 64 + mi * 16 + ((lane >> 4) << 2);
            C[(size_t)(rowb + 0) * N + col] = acc[mi][ni].x + bv;
            C[(size_t)(rowb + 1) * N + col] = acc[mi][ni].y + bv;
            C[(size_t)(rowb + 2) * N + col] = acc[mi][ni].z + bv;
            C[(size_t)(rowb + 3) * N + col] = acc[mi][ni].w + bv;
        }
    }
}

// ---------------------------------------------------------------------------
// LIF time-scan, in place; optionally writes last-timestep spikes to last_out.
// ---------------------------------------------------------------------------
__global__ __launch_bounds__(256)
void lif_scan(float* __restrict__ buf, int BH, float* __restrict__ last_out) {
    int j = blockIdx.x * 256 + threadIdx.x;
    if (j >= BH) return;
    float v = 0.f;
    float last = 0.f;
    for (int t = 0; t < T_; ++t) {
        size_t idx = (size_t)t * BH + j;
        float in = buf[idx];
        v = v + (in - v) * ALPHA;
        bool sp = (v >= THR);
        last = sp ? 1.0f : 0.0f;
        buf[idx] = last;
        v = sp ? 0.0f : v;
    }
    if (last_out) last_out[j] = last;
}

// Folded output weights: Wf = W2 @ Wo (f64 accum), bf = b2 @ Wo + bo.
__global__ __launch_bounds__(256)
void make_wf(const float* __restrict__ W2, const float* __restrict__ Wo,
             const float* __restrict__ b2, const float* __restrict__ bo,
             float* __restrict__ Wf, float* __restrict__ bf) {
    int idx = blockIdx.x * 256 + threadIdx.x;
    if (idx < H_ * O_) {
        int h = idx / O_;
        int o = idx - h * O_;
        double acc = 0.0;
        for (int k = 0; k < H_; ++k)
            acc += (double)W2[(size_t)h * H_ + k] * (double)Wo[(size_t)k * O_ + o];
        Wf[idx] = (float)acc;
    }
    if (idx < O_) {
        double acc = (double)bo[idx];
        for (int h = 0; h < H_; ++h)
            acc += (double)b2[h] * (double)Wo[(size_t)h * O_ + idx];
        bf[idx] = (float)acc;
    }
}

// 3-way bf16 split of W [K][N], written TRANSPOSED: t{0,1,2}[n*K + k].
__device__ inline unsigned short f2bf_rtn(float f) {
    uint32_t u = __float_as_uint(f);
    uint32_t r = (u + 0x7FFFu + ((u >> 16) & 1u)) >> 16;
    return (unsigned short)r;
}

__global__ __launch_bounds__(256)
void split_w(const float* __restrict__ W, unsigned short* __restrict__ t0,
             unsigned short* __restrict__ t1, unsigned short* __restrict__ t2,
             int K, int N) {
    int idx = blockIdx.x * 256 + threadIdx.x;     // idx = n*K + k (write-coalesced)
    if (idx >= K * N) return;
    int n = idx / K;
    int k = idx - n * K;
    float wv = W[(size_t)k * N + n];
    unsigned short b0 = f2bf_rtn(wv);
    float f0 = __uint_as_float((uint32_t)b0 << 16);
    float r1 = wv - f0;
    unsigned short b1 = f2bf_rtn(r1);
    float f1 = __uint_as_float((uint32_t)b1 << 16);
    float r2 = r1 - f1;
    unsigned short b2 = f2bf_rtn(r2);
    t0[idx] = b0; t1[idx] = b1; t2[idx] = b2;
}

// ---------------------------------------------------------------------------
extern "C" void kernel_launch(void* const* d_in, const int* in_sizes, int n_in,
                              void* d_out, int out_size, void* d_ws, size_t ws_size,
                              hipStream_t stream) {
    const float* x  = (const float*)d_in[0];
    const float* We = (const float*)d_in[1];
    const float* be = (const float*)d_in[2];
    const float* W1 = (const float*)d_in[3];
    const float* b1 = (const float*)d_in[4];
    const float* W2 = (const float*)d_in[5];
    const float* b2 = (const float*)d_in[6];
    const float* Wo = (const float*)d_in[7];
    const float* bo = (const float*)d_in[8];

    float* out = (float*)d_out;
    float* so_last = out;                              // [B, O]
    float* S1 = out + (size_t)B_ * O_;                 // [T, B, H]
    float* S2 = S1 + (size_t)T_ * B_ * H_;             // [T, B, H]
    float* SO = S2 + (size_t)T_ * B_ * H_;             // [T, B, O]

    const int TB = T_ * B_;                            // 32768 rows
    dim3 blk(256);

    // ---- workspace layout (bytes) ----
    const size_t off_wf  = 0;                          // Wf fp32   [H][O]
    const size_t off_bf  = (size_t)H_ * O_ * 4;        // bf fp32   [O]
    const size_t off_w1t = off_bf + (size_t)O_ * 4;    // W1t bf16  3x [H][H] (transposed)
    const size_t sz_w1t  = (size_t)H_ * H_ * 2;
    const size_t off_wft = off_w1t + 3 * sz_w1t;       // Wft bf16  3x [O][H] (transposed)
    const size_t sz_wft  = (size_t)H_ * O_ * 2;
    const size_t need    = off_wft + 3 * sz_wft;       // ~11.5 MiB

    // Layer 0: h_pre = relu(x @ We + be)  (fp32, proven)
    gemm128<true, true><<<dim3((TB / 128) * (H_ / 128)), blk, 0, stream>>>(
        x, We, be, S1, TB, H_, I_);
    lif_scan<<<dim3((B_ * H_ + 255) / 256), blk, 0, stream>>>(S1, B_ * H_, nullptr);

    if (ws_size >= need) {
        char* ws = (char*)d_ws;
        float* Wf = (float*)(ws + off_wf);
        float* bf = (float*)(ws + off_bf);
        unsigned short* W1t0 = (unsigned short*)(ws + off_w1t);
        unsigned short* W1t1 = (unsigned short*)(ws + off_w1t + sz_w1t);
        unsigned short* W1t2 = (unsigned short*)(ws + off_w1t + 2 * sz_w1t);
        unsigned short* Wft0 = (unsigned short*)(ws + off_wft);
        unsigned short* Wft1 = (unsigned short*)(ws + off_wft + sz_wft);
        unsigned short* Wft2 = (unsigned short*)(ws + off_wft + 2 * sz_wft);

        // Prep (runs every call; deterministic)
        split_w<<<dim3((H_ * H_ + 255) / 256), blk, 0, stream>>>(
            W1, W1t0, W1t1, W1t2, H_, H_);
        make_wf<<<dim3((H_ * O_ + 255) / 256), blk, 0, stream>>>(
            W2, Wo, b2, bo, Wf, bf);
        split_w<<<dim3((H_ * O_ + 255) / 256), blk, 0, stream>>>(
            Wf, Wft0, Wft1, Wft2, H_, O_);

        // Layer 1: a1 = S1 @ W1 + b1  (bf16 MFMA, 3-split weights)
        gemm_mfma3<<<dim3((TB / 128) * (H_ / 128)), blk, 0, stream>>>(
            S1, W1t0, W1t1, W1t2, b1, S2, TB, H_, H_);
        lif_scan<<<dim3((B_ * H_ + 255) / 256), blk, 0, stream>>>(S2, B_ * H_, nullptr);

        // Layer 2 (folded): a2 = S2 @ (W2@Wo) + (b2@Wo+bo)  (bf16 MFMA, 3-split)
        gemm_mfma3<<<dim3((TB / 128) * (O_ / 128)), blk, 0, stream>>>(
            S2, Wft0, Wft1, Wft2, bf, SO, TB, O_, H_);
        lif_scan<<<dim3((B_ * O_ + 255) / 256), blk, 0, stream>>>(SO, B_ * O_, so_last);
    } else {
        // Fallback: proven fp32 folded path (needs ~2.1 MiB ws)
        float* Wf = (float*)d_ws;
        float* bf = Wf + (size_t)H_ * O_;
        gemm128<false, false><<<dim3((TB / 128) * (H_ / 128)), blk, 0, stream>>>(
            S1, W1, b1, S2, TB, H_, H_);
        lif_scan<<<dim3((B_ * H_ + 255) / 256), blk, 0, stream>>>(S2, B_ * H_, nullptr);
        make_wf<<<dim3((H_ * O_ + 255) / 256), blk, 0, stream>>>(W2, Wo, b2, bo, Wf, bf);
        gemm128<false, false><<<dim3((TB / 128) * (O_ / 128)), blk, 0, stream>>>(
            S2, Wf, bf, SO, TB, O_, H_);
        lif_scan<<<dim3((B_ * O_ + 255) / 256), blk, 0, stream>>>(SO, B_ * O_, so_last);
    }
}

// Round 3
// 762.357 us; speedup vs baseline: 2.8820x; 1.3835x over previous
//
#include <hip/hip_runtime.h>
#include <cstdint>
#include <cstddef>

// Problem constants (match reference)
#define B_ 256
#define T_ 128
#define I_ 512
#define H_ 1024
#define O_ 512
static constexpr float ALPHA = 1.0f / 20.0f;   // DT/TAU
static constexpr float THR   = 1.0f;
static constexpr float S12   = 0.000244140625f; // 2^-12 (exact)

typedef _Float16 f16;
typedef __attribute__((ext_vector_type(8))) _Float16 f16x8;
typedef __attribute__((ext_vector_type(4))) float f32x4;

// ---------------------------------------------------------------------------
// fp32 tiled GEMM (fallback path only)
// ---------------------------------------------------------------------------
template<bool PERM_X, bool RELU>
__global__ __launch_bounds__(256)
void gemm128(const float* __restrict__ A, const float* __restrict__ Bw,
             const float* __restrict__ bias, float* __restrict__ C,
             int M, int N, int K) {
    constexpr int BM = 128, BN = 128, BK = 16, TM = 8, TN = 8;
    __shared__ float As[BK][BM];
    __shared__ float Bs[BK][BN + 4];

    const int tid = threadIdx.x;
    const int ntile = N / BN;
    const int bx = blockIdx.x % ntile;
    const int by = blockIdx.x / ntile;
    const int row0 = by * BM, col0 = bx * BN;
    const int tx = tid & 15;
    const int ty = tid >> 4;

    float acc[TM][TN] = {};

    for (int k0 = 0; k0 < K; k0 += BK) {
#pragma unroll
        for (int p = 0; p < 2; ++p) {
            int f = tid + p * 256;
            int r  = f >> 2;
            int kc = (f & 3) << 2;
            int m = row0 + r;
            const float* arow;
            if (PERM_X) {
                int t = m >> 8;
                int b = m & 255;
                arow = A + (size_t)(b * T_ + t) * K;
            } else {
                arow = A + (size_t)m * K;
            }
            float4 v = *reinterpret_cast<const float4*>(arow + k0 + kc);
            As[kc + 0][r] = v.x;
            As[kc + 1][r] = v.y;
            As[kc + 2][r] = v.z;
            As[kc + 3][r] = v.w;
        }
#pragma unroll
        for (int p = 0; p < 2; ++p) {
            int f = tid + p * 256;
            int r  = f >> 5;
            int nc = (f & 31) << 2;
            float4 v = *reinterpret_cast<const float4*>(Bw + (size_t)(k0 + r) * N + col0 + nc);
            *reinterpret_cast<float4*>(&Bs[r][nc]) = v;
        }
        __syncthreads();

#pragma unroll
        for (int k = 0; k < BK; ++k) {
            float a[TM], b[TN];
#pragma unroll
            for (int i = 0; i < TM; ++i) a[i] = As[k][ty * TM + i];
#pragma unroll
            for (int j = 0; j < TN; ++j) b[j] = Bs[k][tx * TN + j];
#pragma unroll
            for (int i = 0; i < TM; ++i)
#pragma unroll
                for (int j = 0; j < TN; ++j)
                    acc[i][j] += a[i] * b[j];
        }
        __syncthreads();
    }

#pragma unroll
    for (int i = 0; i < TM; ++i) {
        size_t m = (size_t)(row0 + ty * TM + i);
#pragma unroll
        for (int jj = 0; jj < TN; jj += 4) {
            int n = col0 + tx * TN + jj;
            float4 c4;
            float c0 = acc[i][jj + 0] + bias[n + 0];
            float c1 = acc[i][jj + 1] + bias[n + 1];
            float c2 = acc[i][jj + 2] + bias[n + 2];
            float c3 = acc[i][jj + 3] + bias[n + 3];
            if (RELU) {
                c0 = fmaxf(c0, 0.f); c1 = fmaxf(c1, 0.f);
                c2 = fmaxf(c2, 0.f); c3 = fmaxf(c3, 0.f);
            }
            c4.x = c0; c4.y = c1; c4.z = c2; c4.w = c3;
            *reinterpret_cast<float4*>(C + m * N + n) = c4;
        }
    }
}

// ---------------------------------------------------------------------------
// fp16-MFMA GEMM with 2-term scaled fp16 weight split (fp32-equivalent):
//   C = A @ (Bhi + 2^-12 * Blo) + bias            (!SPLITX: A is 0/1 spikes)
//   C = (A0 + 2^-12 A1) @ (Bhi + 2^-12 Blo) + bias (SPLITX: A split in-kernel,
//        dropping the 2^-24 A1@Blo term)
// A fp32 [M][K] (PERM: row m -> x[(m&255)*T + (m>>8)]); B splits fp16 [N][K].
// 128x128 tile, BK=32, 4 waves (2x2 of 64x64), 16x16x32 f16 MFMA.
// Two accumulator groups, combined in epilogue: acc0 + 2^-12 * acc1.
// ---------------------------------------------------------------------------
__device__ inline void gload_lds16(const void* gsrc, void* ldsdst) {
    __builtin_amdgcn_global_load_lds(
        (const __attribute__((address_space(1))) unsigned int*)gsrc,
        (__attribute__((address_space(3))) unsigned int*)ldsdst, 16, 0, 0);
}

template<bool SPLITX, bool PERM, bool RELU>
__global__ __launch_bounds__(256, 2)
void gemm_f16(const float* __restrict__ A,
              const f16* __restrict__ Bhi,   // [N][K]
              const f16* __restrict__ Blo,   // [N][K] (x 2^12)
              const float* __restrict__ bias,
              float* __restrict__ C, int M, int N, int K) {
    constexpr int BK = 32;
    __shared__ f16 Ahi_lds[128 * BK];                    // 8 KB
    __shared__ f16 Alo_lds[SPLITX ? 128 * BK : 8];       // 8 KB (L0 only)
    __shared__ f16 Bhi_lds[128 * BK];                    // 8 KB
    __shared__ f16 Blo_lds[128 * BK];                    // 8 KB

    const int tid  = threadIdx.x;
    const int lane = tid & 63;
    const int w    = tid >> 6;
    const int wr   = w >> 1, wc = w & 1;
    const int ntile = N >> 7;
    const int bx = blockIdx.x % ntile;
    const int by = blockIdx.x / ntile;
    const int row0 = by << 7, col0 = bx << 7;

    f32x4 acc0[4][4], acc1[4][4];
#pragma unroll
    for (int mi = 0; mi < 4; ++mi)
#pragma unroll
        for (int ni = 0; ni < 4; ++ni) {
            acc0[mi][ni] = {0.f, 0.f, 0.f, 0.f};
            acc1[mi][ni] = {0.f, 0.f, 0.f, 0.f};
        }

    for (int k0 = 0; k0 < K; k0 += BK) {
        // --- stage B splits (global_load_lds, dest = chunk base + lane*16) ---
#pragma unroll
        for (int p = 0; p < 2; ++p) {
            int chunk = w * 2 + p;                 // 0..7, 1 KiB each
            int r  = chunk * 16 + (lane >> 2);     // n within tile
            int kq = lane & 3;                     // 16B quad along k
            size_t off = (size_t)(col0 + r) * K + k0 + kq * 8;
            gload_lds16(Bhi + off, &Bhi_lds[chunk * 512]);
            gload_lds16(Blo + off, &Blo_lds[chunk * 512]);
        }
        // --- stage A: fp32 -> fp16 (spikes exact; SPLITX: 2-term split) ---
#pragma unroll
        for (int p = 0; p < 4; ++p) {
            int c = tid + p * 256;       // 1024 float4 chunks
            int r = c >> 3;              // row 0..127
            int q = c & 7;               // float4 along k
            int m = row0 + r;
            const float* arow;
            if (PERM) arow = A + (size_t)((m & 255) * T_ + (m >> 8)) * K;
            else      arow = A + (size_t)m * K;
            float4 v = *reinterpret_cast<const float4*>(arow + k0 + q * 4);
            union { f16 h[4]; uint2 u; } hi;
            hi.h[0] = (f16)v.x; hi.h[1] = (f16)v.y;
            hi.h[2] = (f16)v.z; hi.h[3] = (f16)v.w;
            *reinterpret_cast<uint2*>(&Ahi_lds[r * BK + q * 4]) = hi.u;
            if (SPLITX) {
                union { f16 h[4]; uint2 u; } lo;
                lo.h[0] = (f16)((v.x - (float)hi.h[0]) * 4096.0f);
                lo.h[1] = (f16)((v.y - (float)hi.h[1]) * 4096.0f);
                lo.h[2] = (f16)((v.z - (float)hi.h[2]) * 4096.0f);
                lo.h[3] = (f16)((v.w - (float)hi.h[3]) * 4096.0f);
                *reinterpret_cast<uint2*>(&Alo_lds[r * BK + q * 4]) = lo.u;
            }
        }
        __syncthreads();

        // --- fragments + MFMA ---
        f16x8 ahi[4], alo[4];
#pragma unroll
        for (int mi = 0; mi < 4; ++mi) {
            int ar = (wr * 64 + mi * 16 + (lane & 15)) * BK + (lane >> 4) * 8;
            ahi[mi] = *reinterpret_cast<const f16x8*>(&Ahi_lds[ar]);
            if (SPLITX) alo[mi] = *reinterpret_cast<const f16x8*>(&Alo_lds[ar]);
        }
#pragma unroll
        for (int ni = 0; ni < 4; ++ni) {
            int br = (wc * 64 + ni * 16 + (lane & 15)) * BK + (lane >> 4) * 8;
            f16x8 bh = *reinterpret_cast<const f16x8*>(&Bhi_lds[br]);
            f16x8 bl = *reinterpret_cast<const f16x8*>(&Blo_lds[br]);
#pragma unroll
            for (int mi = 0; mi < 4; ++mi) {
                acc0[mi][ni] = __builtin_amdgcn_mfma_f32_16x16x32_f16(
                    ahi[mi], bh, acc0[mi][ni], 0, 0, 0);
                acc1[mi][ni] = __builtin_amdgcn_mfma_f32_16x16x32_f16(
                    ahi[mi], bl, acc1[mi][ni], 0, 0, 0);
                if (SPLITX)
                    acc1[mi][ni] = __builtin_amdgcn_mfma_f32_16x16x32_f16(
                        alo[mi], bh, acc1[mi][ni], 0, 0, 0);
            }
        }
        __syncthreads();
    }

    // --- epilogue: C = acc0 + 2^-12*acc1 + bias (C/D: col=lane&15, row=(lane>>4)*4+r)
#pragma unroll
    for (int ni = 0; ni < 4; ++ni) {
        int col = col0 + wc * 64 + ni * 16 + (lane & 15);
        float bv = bias[col];
#pragma unroll
        for (int mi = 0; mi < 4; ++mi) {
            int rowb = row0 + wr * 64 + mi * 16 + ((lane >> 4) << 2);
#pragma unroll
            for (int r = 0; r < 4; ++r) {
                float cv = acc0[mi][ni][r] + S12 * acc1[mi][ni][r] + bv;
                if (RELU) cv = fmaxf(cv, 0.f);
                C[(size_t)(rowb + r) * N + col] = cv;
            }
        }
    }
}

// ---------------------------------------------------------------------------
// LIF time-scan, in place; optionally writes last-timestep spikes to last_out.
// ---------------------------------------------------------------------------
__global__ __launch_bounds__(256)
void lif_scan(float* __restrict__ buf, int BH, float* __restrict__ last_out) {
    int j = blockIdx.x * 256 + threadIdx.x;
    if (j >= BH) return;
    float v = 0.f;
    float last = 0.f;
    for (int t = 0; t < T_; ++t) {
        size_t idx = (size_t)t * BH + j;
        float in = buf[idx];
        v = v + (in - v) * ALPHA;
        bool sp = (v >= THR);
        last = sp ? 1.0f : 0.0f;
        buf[idx] = last;
        v = sp ? 0.0f : v;
    }
    if (last_out) last_out[j] = last;
}

// ---------------------------------------------------------------------------
// Tiled f64-accumulation fold: Wf[h][o] = sum_k W2[h][k]*Wo[k][o]  (fp32 out)
// Block computes [32 h x 64 o]; grid = (H/32)*(O/64) = 256 blocks.
// ---------------------------------------------------------------------------
__global__ __launch_bounds__(256)
void make_wf2(const float* __restrict__ W2, const float* __restrict__ Wo,
              float* __restrict__ Wf) {
    __shared__ float w2s[64][33];   // [k][h]
    __shared__ float wos[64][68];   // [k][o]
    const int tid = threadIdx.x;
    const int ht = blockIdx.x >> 3, ot = blockIdx.x & 7;
    const int h0 = ht * 32, o0 = ot * 64;
    const int th = tid >> 3;        // 0..31 -> h
    const int to = tid & 7;         // 0..7  -> o block of 8

    double acc[8] = {0, 0, 0, 0, 0, 0, 0, 0};

    for (int k0 = 0; k0 < H_; k0 += 64) {
        // stage W2 [32h][64k] -> w2s[k][h]
#pragma unroll
        for (int p = 0; p < 2; ++p) {
            int f = tid + p * 256;
            int i = f >> 4;              // h 0..31
            int j4 = (f & 15) << 2;      // k
            float4 v = *reinterpret_cast<const float4*>(
                W2 + (size_t)(h0 + i) * H_ + k0 + j4);
            w2s[j4 + 0][i] = v.x; w2s[j4 + 1][i] = v.y;
            w2s[j4 + 2][i] = v.z; w2s[j4 + 3][i] = v.w;
        }
        // stage Wo [64k][64o] -> wos[k][o]
#pragma unroll
        for (int p = 0; p < 4; ++p) {
            int f = tid + p * 256;
            int r = f >> 4;              // k 0..63
            int c4 = (f & 15) << 2;      // o
            float4 v = *reinterpret_cast<const float4*>(
                Wo + (size_t)(k0 + r) * O_ + o0 + c4);
            wos[r][c4 + 0] = v.x; wos[r][c4 + 1] = v.y;
            wos[r][c4 + 2] = v.z; wos[r][c4 + 3] = v.w;
        }
        __syncthreads();

#pragma unroll 8
        for (int k = 0; k < 64; ++k) {
            double a = (double)w2s[k][th];
#pragma unroll
            for (int j = 0; j < 8; ++j)
                acc[j] += a * (double)wos[k][to * 8 + j];
        }
        __syncthreads();
    }
#pragma unroll
    for (int j = 0; j < 8; ++j)
        Wf[(size_t)(h0 + th) * O_ + o0 + to * 8 + j] = (float)acc[j];
}

// bf[o] = bo[o] + sum_h b2[h]*Wo[h][o]  (f64 accum)
__global__ __launch_bounds__(256)
void make_bf(const float* __restrict__ Wo, const float* __restrict__ b2,
             const float* __restrict__ bo, float* __restrict__ bf) {
    int o = blockIdx.x * 256 + threadIdx.x;
    if (o >= O_) return;
    double acc = (double)bo[o];
    for (int h = 0; h < H_; ++h)
        acc += (double)b2[h] * (double)Wo[(size_t)h * O_ + o];
    bf[o] = (float)acc;
}

// 2-term scaled fp16 split of W [K][N], written TRANSPOSED [N][K]:
//   W = hi + 2^-12 * lo  (lo stored x 2^12, stays fp16-normal)
__global__ __launch_bounds__(256)
void split_w16(const float* __restrict__ W, f16* __restrict__ hi,
               f16* __restrict__ lo, int K, int N) {
    int idx = blockIdx.x * 256 + threadIdx.x;     // idx = n*K + k (write-coalesced)
    if (idx >= K * N) return;
    int n = idx / K;
    int k = idx - n * K;
    float wv = W[(size_t)k * N + n];
    f16 h0 = (f16)wv;                              // RTN
    float r = (wv - (float)h0) * 4096.0f;          // exact
    f16 h1 = (f16)r;
    hi[idx] = h0; lo[idx] = h1;
}

// ---------------------------------------------------------------------------
extern "C" void kernel_launch(void* const* d_in, const int* in_sizes, int n_in,
                              void* d_out, int out_size, void* d_ws, size_t ws_size,
                              hipStream_t stream) {
    const float* x  = (const float*)d_in[0];
    const float* We = (const float*)d_in[1];
    const float* be = (const float*)d_in[2];
    const float* W1 = (const float*)d_in[3];
    const float* b1 = (const float*)d_in[4];
    const float* W2 = (const float*)d_in[5];
    const float* b2 = (const float*)d_in[6];
    const float* Wo = (const float*)d_in[7];
    const float* bo = (const float*)d_in[8];

    float* out = (float*)d_out;
    float* so_last = out;                              // [B, O]
    float* S1 = out + (size_t)B_ * O_;                 // [T, B, H]
    float* S2 = S1 + (size_t)T_ * B_ * H_;             // [T, B, H]
    float* SO = S2 + (size_t)T_ * B_ * H_;             // [T, B, O]

    const int TB = T_ * B_;                            // 32768 rows
    dim3 blk(256);

    // ---- workspace layout (bytes) ----
    const size_t sz_we  = (size_t)I_ * H_ * 2;         // 1 MiB per split
    const size_t sz_w1  = (size_t)H_ * H_ * 2;         // 2 MiB per split
    const size_t sz_wf  = (size_t)H_ * O_ * 2;         // 1 MiB per split
    const size_t off_weh = 0;
    const size_t off_wel = off_weh + sz_we;
    const size_t off_w1h = off_wel + sz_we;
    const size_t off_w1l = off_w1h + sz_w1;
    const size_t off_wf32 = off_w1l + sz_w1;           // Wf fp32: 2 MiB
    const size_t off_bf   = off_wf32 + (size_t)H_ * O_ * 4;
    const size_t off_wfh  = off_bf + (size_t)O_ * 4;
    const size_t off_wfl  = off_wfh + sz_wf;
    const size_t need     = off_wfl + sz_wf;           // ~10.1 MiB

    if (ws_size >= need) {
        char* ws = (char*)d_ws;
        f16*   weh = (f16*)(ws + off_weh);
        f16*   wel = (f16*)(ws + off_wel);
        f16*   w1h = (f16*)(ws + off_w1h);
        f16*   w1l = (f16*)(ws + off_w1l);
        float* Wf  = (float*)(ws + off_wf32);
        float* bf  = (float*)(ws + off_bf);
        f16*   wfh = (f16*)(ws + off_wfh);
        f16*   wfl = (f16*)(ws + off_wfl);

        // ---- prep (every call; deterministic) ----
        split_w16<<<dim3((I_ * H_ + 255) / 256), blk, 0, stream>>>(We, weh, wel, I_, H_);
        split_w16<<<dim3((H_ * H_ + 255) / 256), blk, 0, stream>>>(W1, w1h, w1l, H_, H_);
        make_wf2<<<dim3(256), blk, 0, stream>>>(W2, Wo, Wf);
        make_bf<<<dim3(2), blk, 0, stream>>>(Wo, b2, bo, bf);
        split_w16<<<dim3((H_ * O_ + 255) / 256), blk, 0, stream>>>(Wf, wfh, wfl, H_, O_);

        // ---- Layer 0: h = relu(x @ We + be)  (split-A fp16 MFMA) ----
        gemm_f16<true, true, true><<<dim3((TB / 128) * (H_ / 128)), blk, 0, stream>>>(
            x, weh, wel, be, S1, TB, H_, I_);
        lif_scan<<<dim3((B_ * H_ + 255) / 256), blk, 0, stream>>>(S1, B_ * H_, nullptr);

        // ---- Layer 1: a1 = S1 @ W1 + b1 ----
        gemm_f16<false, false, false><<<dim3((TB / 128) * (H_ / 128)), blk, 0, stream>>>(
            S1, w1h, w1l, b1, S2, TB, H_, H_);
        lif_scan<<<dim3((B_ * H_ + 255) / 256), blk, 0, stream>>>(S2, B_ * H_, nullptr);

        // ---- Layer 2 (folded): a2 = S2 @ (W2@Wo) + (b2@Wo+bo) ----
        gemm_f16<false, false, false><<<dim3((TB / 128) * (O_ / 128)), blk, 0, stream>>>(
            S2, wfh, wfl, bf, SO, TB, O_, H_);
        lif_scan<<<dim3((B_ * O_ + 255) / 256), blk, 0, stream>>>(SO, B_ * O_, so_last);
    } else {
        // ---- fallback: proven fp32 folded path (needs ~2.1 MiB ws) ----
        float* Wf = (float*)d_ws;
        float* bf = Wf + (size_t)H_ * O_;
        gemm128<true, true><<<dim3((TB / 128) * (H_ / 128)), blk, 0, stream>>>(
            x, We, be, S1, TB, H_, I_);
        lif_scan<<<dim3((B_ * H_ + 255) / 256), blk, 0, stream>>>(S1, B_ * H_, nullptr);
        gemm128<false, false><<<dim3((TB / 128) * (H_ / 128)), blk, 0, stream>>>(
            S1, W1, b1, S2, TB, H_, H_);
        lif_scan<<<dim3((B_ * H_ + 255) / 256), blk, 0, stream>>>(S2, B_ * H_, nullptr);
        make_wf2<<<dim3(256), blk, 0, stream>>>(W2, Wo, Wf);
        make_bf<<<dim3(2), blk, 0, stream>>>(Wo, b2, bo, bf);
        gemm128<false, false><<<dim3((TB / 128) * (O_ / 128)), blk, 0, stream>>>(
            S2, Wf, bf, SO, TB, O_, H_);
        lif_scan<<<dim3((B_ * O_ + 255) / 256), blk, 0, stream>>>(SO, B_ * O_, so_last);
    }
}

// Round 4
// 643.395 us; speedup vs baseline: 3.4149x; 1.1849x over previous
//
#include <hip/hip_runtime.h>
#include <cstdint>
#include <cstddef>

// Problem constants (match reference)
#define B_ 256
#define T_ 128
#define I_ 512
#define H_ 1024
#define O_ 512
static constexpr float ALPHA = 1.0f / 20.0f;   // DT/TAU
static constexpr float THR   = 1.0f;
static constexpr float S12   = 0.000244140625f; // 2^-12 (exact)

typedef _Float16 f16;
typedef __attribute__((ext_vector_type(8))) _Float16 f16x8;
typedef __attribute__((ext_vector_type(4))) float f32x4;

// ---------------------------------------------------------------------------
// fp32 tiled GEMM (fallback path only)
// ---------------------------------------------------------------------------
template<bool PERM_X, bool RELU>
__global__ __launch_bounds__(256)
void gemm128(const float* __restrict__ A, const float* __restrict__ Bw,
             const float* __restrict__ bias, float* __restrict__ C,
             int M, int N, int K) {
    constexpr int BM = 128, BN = 128, BK = 16, TM = 8, TN = 8;
    __shared__ float As[BK][BM];
    __shared__ float Bs[BK][BN + 4];

    const int tid = threadIdx.x;
    const int ntile = N / BN;
    const int bx = blockIdx.x % ntile;
    const int by = blockIdx.x / ntile;
    const int row0 = by * BM, col0 = bx * BN;
    const int tx = tid & 15;
    const int ty = tid >> 4;

    float acc[TM][TN] = {};

    for (int k0 = 0; k0 < K; k0 += BK) {
#pragma unroll
        for (int p = 0; p < 2; ++p) {
            int f = tid + p * 256;
            int r  = f >> 2;
            int kc = (f & 3) << 2;
            int m = row0 + r;
            const float* arow;
            if (PERM_X) {
                int t = m >> 8;
                int b = m & 255;
                arow = A + (size_t)(b * T_ + t) * K;
            } else {
                arow = A + (size_t)m * K;
            }
            float4 v = *reinterpret_cast<const float4*>(arow + k0 + kc);
            As[kc + 0][r] = v.x;
            As[kc + 1][r] = v.y;
            As[kc + 2][r] = v.z;
            As[kc + 3][r] = v.w;
        }
#pragma unroll
        for (int p = 0; p < 2; ++p) {
            int f = tid + p * 256;
            int r  = f >> 5;
            int nc = (f & 31) << 2;
            float4 v = *reinterpret_cast<const float4*>(Bw + (size_t)(k0 + r) * N + col0 + nc);
            *reinterpret_cast<float4*>(&Bs[r][nc]) = v;
        }
        __syncthreads();

#pragma unroll
        for (int k = 0; k < BK; ++k) {
            float a[TM], b[TN];
#pragma unroll
            for (int i = 0; i < TM; ++i) a[i] = As[k][ty * TM + i];
#pragma unroll
            for (int j = 0; j < TN; ++j) b[j] = Bs[k][tx * TN + j];
#pragma unroll
            for (int i = 0; i < TM; ++i)
#pragma unroll
                for (int j = 0; j < TN; ++j)
                    acc[i][j] += a[i] * b[j];
        }
        __syncthreads();
    }

#pragma unroll
    for (int i = 0; i < TM; ++i) {
        size_t m = (size_t)(row0 + ty * TM + i);
#pragma unroll
        for (int jj = 0; jj < TN; jj += 4) {
            int n = col0 + tx * TN + jj;
            float4 c4;
            float c0 = acc[i][jj + 0] + bias[n + 0];
            float c1 = acc[i][jj + 1] + bias[n + 1];
            float c2 = acc[i][jj + 2] + bias[n + 2];
            float c3 = acc[i][jj + 3] + bias[n + 3];
            if (RELU) {
                c0 = fmaxf(c0, 0.f); c1 = fmaxf(c1, 0.f);
                c2 = fmaxf(c2, 0.f); c3 = fmaxf(c3, 0.f);
            }
            c4.x = c0; c4.y = c1; c4.z = c2; c4.w = c3;
            *reinterpret_cast<float4*>(C + m * N + n) = c4;
        }
    }
}

// ---------------------------------------------------------------------------
// Fused fp16-MFMA GEMM + LIF time-scan.
//   pre[t][n] = A @ (Bhi + 2^-12 Blo) + bias   (SPLITX: + 2^-12 A1@Bhi term)
//   then (optional ReLU), then LIF scan over t; writes ONLY spikes.
// One block = ALL 128 timesteps of ONE batch element x 128 features.
//   PERM (layer 0): A row r -> x[b][r][:]   (contiguous per block)
//   else          : A row r -> S[r][b][:]   (spikes from previous layer)
// 4 waves (2x2 of 64x64), BK=32, 16x16x32 f16 MFMA, 2 accumulator groups.
// Epilogue: acc -> LDS Cs[128][132] (union with staging) -> 128-thread scan.
// ---------------------------------------------------------------------------
__device__ inline void gload_lds16(const void* gsrc, void* ldsdst) {
    __builtin_amdgcn_global_load_lds(
        (const __attribute__((address_space(1))) unsigned int*)gsrc,
        (__attribute__((address_space(3))) unsigned int*)ldsdst, 16, 0, 0);
}

template<bool SPLITX, bool PERM, bool RELU, bool WRITE_LAST>
__global__ __launch_bounds__(256, 2)
void gemm_lif(const float* __restrict__ A,
              const f16* __restrict__ Bhi,   // [N][K]
              const f16* __restrict__ Blo,   // [N][K] (x 2^12)
              const float* __restrict__ bias,
              float* __restrict__ S,         // [T][B][N] spikes out
              float* __restrict__ last_out,  // [B][N] (WRITE_LAST)
              int N, int K) {
    constexpr int BK = 32;
    // union: staging (Ahi 8K | Bhi 8K | Blo 8K | Alo 8K) vs Cs[128][132] f32
    __shared__ __align__(16) char smem[128 * 132 * 4];
    f16* Ah = (f16*)smem;            // 4096 f16
    f16* Bh = Ah + 4096;
    f16* Bl = Bh + 4096;
    f16* Al = Bl + 4096;             // used only when SPLITX
    float (*Cs)[132] = (float (*)[132])smem;

    const int tid  = threadIdx.x;
    const int lane = tid & 63;
    const int w    = tid >> 6;
    const int wr   = w >> 1, wc = w & 1;
    const int ntile = N >> 7;
    const int bx = blockIdx.x % ntile;      // feature tile
    const int b  = blockIdx.x / ntile;      // batch element
    const int col0 = bx << 7;

    f32x4 acc0[4][4], acc1[4][4];
#pragma unroll
    for (int mi = 0; mi < 4; ++mi)
#pragma unroll
        for (int ni = 0; ni < 4; ++ni) {
            acc0[mi][ni] = {0.f, 0.f, 0.f, 0.f};
            acc1[mi][ni] = {0.f, 0.f, 0.f, 0.f};
        }

    for (int k0 = 0; k0 < K; k0 += BK) {
        // --- stage B splits via global_load_lds ---
#pragma unroll
        for (int p = 0; p < 2; ++p) {
            int chunk = w * 2 + p;                 // 0..7, 1 KiB each
            int r  = chunk * 16 + (lane >> 2);     // n within tile
            int kq = lane & 3;                     // 16B quad along k
            size_t off = (size_t)(col0 + r) * K + k0 + kq * 8;
            gload_lds16(Bhi + off, &Bh[chunk * 512]);
            gload_lds16(Blo + off, &Bl[chunk * 512]);
        }
        // --- stage A rows (r = timestep): fp32 -> fp16 ---
#pragma unroll
        for (int p = 0; p < 4; ++p) {
            int c = tid + p * 256;       // 1024 float4 chunks
            int r = c >> 3;              // row (=t) 0..127
            int q = c & 7;               // float4 along k
            const float* arow;
            if (PERM) arow = A + (size_t)(b * T_ + r) * K;
            else      arow = A + (size_t)(r * B_ + b) * K;
            float4 v = *reinterpret_cast<const float4*>(arow + k0 + q * 4);
            union { f16 h[4]; uint2 u; } hi;
            hi.h[0] = (f16)v.x; hi.h[1] = (f16)v.y;
            hi.h[2] = (f16)v.z; hi.h[3] = (f16)v.w;
            *reinterpret_cast<uint2*>(&Ah[r * BK + q * 4]) = hi.u;
            if (SPLITX) {
                union { f16 h[4]; uint2 u; } lo;
                lo.h[0] = (f16)((v.x - (float)hi.h[0]) * 4096.0f);
                lo.h[1] = (f16)((v.y - (float)hi.h[1]) * 4096.0f);
                lo.h[2] = (f16)((v.z - (float)hi.h[2]) * 4096.0f);
                lo.h[3] = (f16)((v.w - (float)hi.h[3]) * 4096.0f);
                *reinterpret_cast<uint2*>(&Al[r * BK + q * 4]) = lo.u;
            }
        }
        __syncthreads();

        // --- fragments + MFMA ---
        f16x8 ahi[4], alo[4];
#pragma unroll
        for (int mi = 0; mi < 4; ++mi) {
            int ar = (wr * 64 + mi * 16 + (lane & 15)) * BK + (lane >> 4) * 8;
            ahi[mi] = *reinterpret_cast<const f16x8*>(&Ah[ar]);
            if (SPLITX) alo[mi] = *reinterpret_cast<const f16x8*>(&Al[ar]);
        }
#pragma unroll
        for (int ni = 0; ni < 4; ++ni) {
            int br = (wc * 64 + ni * 16 + (lane & 15)) * BK + (lane >> 4) * 8;
            f16x8 bh = *reinterpret_cast<const f16x8*>(&Bh[br]);
            f16x8 bl = *reinterpret_cast<const f16x8*>(&Bl[br]);
#pragma unroll
            for (int mi = 0; mi < 4; ++mi) {
                acc0[mi][ni] = __builtin_amdgcn_mfma_f32_16x16x32_f16(
                    ahi[mi], bh, acc0[mi][ni], 0, 0, 0);
                acc1[mi][ni] = __builtin_amdgcn_mfma_f32_16x16x32_f16(
                    ahi[mi], bl, acc1[mi][ni], 0, 0, 0);
                if (SPLITX)
                    acc1[mi][ni] = __builtin_amdgcn_mfma_f32_16x16x32_f16(
                        alo[mi], bh, acc1[mi][ni], 0, 0, 0);
            }
        }
        __syncthreads();
    }

    // --- epilogue 1: combine splits + bias (+ReLU), transpose into LDS ---
    // C/D frag: col = lane&15, row = (lane>>4)*4 + r
#pragma unroll
    for (int ni = 0; ni < 4; ++ni) {
        int col = wc * 64 + ni * 16 + (lane & 15);
        float bv = bias[col0 + col];
#pragma unroll
        for (int mi = 0; mi < 4; ++mi) {
            int rowb = wr * 64 + mi * 16 + ((lane >> 4) << 2);
#pragma unroll
            for (int r = 0; r < 4; ++r) {
                float cv = acc0[mi][ni][r] + S12 * acc1[mi][ni][r] + bv;
                if (RELU) cv = fmaxf(cv, 0.f);
                Cs[rowb + r][col] = cv;
            }
        }
    }
    __syncthreads();

    // --- epilogue 2: LIF scan over t (rows of Cs), write spikes only ---
    if (tid < 128) {
        float* Sp = S + (size_t)b * N + col0 + tid;
        const size_t tstride = (size_t)B_ * N;
        float v = 0.f, s = 0.f;
#pragma unroll 4
        for (int t = 0; t < T_; ++t) {
            float in = Cs[t][tid];
            v = v + (in - v) * ALPHA;
            bool sp = (v >= THR);
            s = sp ? 1.0f : 0.0f;
            Sp[(size_t)t * tstride] = s;
            v = sp ? 0.0f : v;
        }
        if (WRITE_LAST) last_out[(size_t)b * N + col0 + tid] = s;
    }
}

// ---------------------------------------------------------------------------
// LIF time-scan (fallback path), in place; optionally writes last spikes.
// ---------------------------------------------------------------------------
__global__ __launch_bounds__(256)
void lif_scan(float* __restrict__ buf, int BH, float* __restrict__ last_out) {
    int j = blockIdx.x * 256 + threadIdx.x;
    if (j >= BH) return;
    float v = 0.f;
    float last = 0.f;
    for (int t = 0; t < T_; ++t) {
        size_t idx = (size_t)t * BH + j;
        float in = buf[idx];
        v = v + (in - v) * ALPHA;
        bool sp = (v >= THR);
        last = sp ? 1.0f : 0.0f;
        buf[idx] = last;
        v = sp ? 0.0f : v;
    }
    if (last_out) last_out[j] = last;
}

// ---------------------------------------------------------------------------
// Tiled f64-accumulation fold: Wf[h][o] = sum_k W2[h][k]*Wo[k][o]  (fp32 out)
// ---------------------------------------------------------------------------
__global__ __launch_bounds__(256)
void make_wf2(const float* __restrict__ W2, const float* __restrict__ Wo,
              float* __restrict__ Wf) {
    __shared__ float w2s[64][33];   // [k][h]
    __shared__ float wos[64][68];   // [k][o]
    const int tid = threadIdx.x;
    const int ht = blockIdx.x >> 3, ot = blockIdx.x & 7;
    const int h0 = ht * 32, o0 = ot * 64;
    const int th = tid >> 3;
    const int to = tid & 7;

    double acc[8] = {0, 0, 0, 0, 0, 0, 0, 0};

    for (int k0 = 0; k0 < H_; k0 += 64) {
#pragma unroll
        for (int p = 0; p < 2; ++p) {
            int f = tid + p * 256;
            int i = f >> 4;
            int j4 = (f & 15) << 2;
            float4 v = *reinterpret_cast<const float4*>(
                W2 + (size_t)(h0 + i) * H_ + k0 + j4);
            w2s[j4 + 0][i] = v.x; w2s[j4 + 1][i] = v.y;
            w2s[j4 + 2][i] = v.z; w2s[j4 + 3][i] = v.w;
        }
#pragma unroll
        for (int p = 0; p < 4; ++p) {
            int f = tid + p * 256;
            int r = f >> 4;
            int c4 = (f & 15) << 2;
            float4 v = *reinterpret_cast<const float4*>(
                Wo + (size_t)(k0 + r) * O_ + o0 + c4);
            wos[r][c4 + 0] = v.x; wos[r][c4 + 1] = v.y;
            wos[r][c4 + 2] = v.z; wos[r][c4 + 3] = v.w;
        }
        __syncthreads();

#pragma unroll 8
        for (int k = 0; k < 64; ++k) {
            double a = (double)w2s[k][th];
#pragma unroll
            for (int j = 0; j < 8; ++j)
                acc[j] += a * (double)wos[k][to * 8 + j];
        }
        __syncthreads();
    }
#pragma unroll
    for (int j = 0; j < 8; ++j)
        Wf[(size_t)(h0 + th) * O_ + o0 + to * 8 + j] = (float)acc[j];
}

// bf[o] = bo[o] + sum_h b2[h]*Wo[h][o]  (f64 accum)
__global__ __launch_bounds__(256)
void make_bf(const float* __restrict__ Wo, const float* __restrict__ b2,
             const float* __restrict__ bo, float* __restrict__ bf) {
    int o = blockIdx.x * 256 + threadIdx.x;
    if (o >= O_) return;
    double acc = (double)bo[o];
    for (int h = 0; h < H_; ++h)
        acc += (double)b2[h] * (double)Wo[(size_t)h * O_ + o];
    bf[o] = (float)acc;
}

// 2-term scaled fp16 split of W [K][N], written TRANSPOSED [N][K]:
//   W = hi + 2^-12 * lo  (lo stored x 2^12, stays fp16-normal)
__global__ __launch_bounds__(256)
void split_w16(const float* __restrict__ W, f16* __restrict__ hi,
               f16* __restrict__ lo, int K, int N) {
    int idx = blockIdx.x * 256 + threadIdx.x;     // idx = n*K + k
    if (idx >= K * N) return;
    int n = idx / K;
    int k = idx - n * K;
    float wv = W[(size_t)k * N + n];
    f16 h0 = (f16)wv;
    float r = (wv - (float)h0) * 4096.0f;
    f16 h1 = (f16)r;
    hi[idx] = h0; lo[idx] = h1;
}

// ---------------------------------------------------------------------------
extern "C" void kernel_launch(void* const* d_in, const int* in_sizes, int n_in,
                              void* d_out, int out_size, void* d_ws, size_t ws_size,
                              hipStream_t stream) {
    const float* x  = (const float*)d_in[0];
    const float* We = (const float*)d_in[1];
    const float* be = (const float*)d_in[2];
    const float* W1 = (const float*)d_in[3];
    const float* b1 = (const float*)d_in[4];
    const float* W2 = (const float*)d_in[5];
    const float* b2 = (const float*)d_in[6];
    const float* Wo = (const float*)d_in[7];
    const float* bo = (const float*)d_in[8];

    float* out = (float*)d_out;
    float* so_last = out;                              // [B, O]
    float* S1 = out + (size_t)B_ * O_;                 // [T, B, H]
    float* S2 = S1 + (size_t)T_ * B_ * H_;             // [T, B, H]
    float* SO = S2 + (size_t)T_ * B_ * H_;             // [T, B, O]

    const int TB = T_ * B_;
    dim3 blk(256);

    // ---- workspace layout (bytes) ----
    const size_t sz_we  = (size_t)I_ * H_ * 2;
    const size_t sz_w1  = (size_t)H_ * H_ * 2;
    const size_t sz_wf  = (size_t)H_ * O_ * 2;
    const size_t off_weh = 0;
    const size_t off_wel = off_weh + sz_we;
    const size_t off_w1h = off_wel + sz_we;
    const size_t off_w1l = off_w1h + sz_w1;
    const size_t off_wf32 = off_w1l + sz_w1;
    const size_t off_bf   = off_wf32 + (size_t)H_ * O_ * 4;
    const size_t off_wfh  = off_bf + (size_t)O_ * 4;
    const size_t off_wfl  = off_wfh + sz_wf;
    const size_t need     = off_wfl + sz_wf;           // ~10.1 MiB

    if (ws_size >= need) {
        char* ws = (char*)d_ws;
        f16*   weh = (f16*)(ws + off_weh);
        f16*   wel = (f16*)(ws + off_wel);
        f16*   w1h = (f16*)(ws + off_w1h);
        f16*   w1l = (f16*)(ws + off_w1l);
        float* Wf  = (float*)(ws + off_wf32);
        float* bf  = (float*)(ws + off_bf);
        f16*   wfh = (f16*)(ws + off_wfh);
        f16*   wfl = (f16*)(ws + off_wfl);

        // ---- prep (every call; deterministic) ----
        split_w16<<<dim3((I_ * H_ + 255) / 256), blk, 0, stream>>>(We, weh, wel, I_, H_);
        split_w16<<<dim3((H_ * H_ + 255) / 256), blk, 0, stream>>>(W1, w1h, w1l, H_, H_);
        make_wf2<<<dim3(256), blk, 0, stream>>>(W2, Wo, Wf);
        make_bf<<<dim3(2), blk, 0, stream>>>(Wo, b2, bo, bf);
        split_w16<<<dim3((H_ * O_ + 255) / 256), blk, 0, stream>>>(Wf, wfh, wfl, H_, O_);

        // ---- Layer 0: S1 = LIF(relu(x @ We + be))   (fused) ----
        gemm_lif<true, true, true, false><<<dim3(B_ * (H_ / 128)), blk, 0, stream>>>(
            x, weh, wel, be, S1, nullptr, H_, I_);

        // ---- Layer 1: S2 = LIF(S1 @ W1 + b1)        (fused) ----
        gemm_lif<false, false, false, false><<<dim3(B_ * (H_ / 128)), blk, 0, stream>>>(
            S1, w1h, w1l, b1, S2, nullptr, H_, H_);

        // ---- Layer 2: SO = LIF(S2 @ (W2@Wo) + bf), so_last = SO[T-1] ----
        gemm_lif<false, false, false, true><<<dim3(B_ * (O_ / 128)), blk, 0, stream>>>(
            S2, wfh, wfl, bf, SO, so_last, O_, H_);
    } else {
        // ---- fallback: proven fp32 folded path (needs ~2.1 MiB ws) ----
        float* Wf = (float*)d_ws;
        float* bf = Wf + (size_t)H_ * O_;
        gemm128<true, true><<<dim3((TB / 128) * (H_ / 128)), blk, 0, stream>>>(
            x, We, be, S1, TB, H_, I_);
        lif_scan<<<dim3((B_ * H_ + 255) / 256), blk, 0, stream>>>(S1, B_ * H_, nullptr);
        gemm128<false, false><<<dim3((TB / 128) * (H_ / 128)), blk, 0, stream>>>(
            S1, W1, b1, S2, TB, H_, H_);
        lif_scan<<<dim3((B_ * H_ + 255) / 256), blk, 0, stream>>>(S2, B_ * H_, nullptr);
        make_wf2<<<dim3(256), blk, 0, stream>>>(W2, Wo, Wf);
        make_bf<<<dim3(2), blk, 0, stream>>>(Wo, b2, bo, bf);
        gemm128<false, false><<<dim3((TB / 128) * (O_ / 128)), blk, 0, stream>>>(
            S2, Wf, bf, SO, TB, O_, H_);
        lif_scan<<<dim3((B_ * O_ + 255) / 256), blk, 0, stream>>>(SO, B_ * O_, so_last);
    }
}